// Round 4
// baseline (854.504 us; speedup 1.0000x reference)
//
#include <hip/hip_runtime.h>

// N=100000 nodes, E=1600000 edges, D=64.
#define D_FEAT 64
#define E_BLK 16384          // edges per partition/hist block
#define MAXB 512             // max buckets supported (nb = ceil(N/256) = 391)

// ---------------- K1: per-block bucket histogram (no atomics to global) ----
__global__ void hist_kernel(const int* __restrict__ row, int* __restrict__ hist_global,
                            int n_edges, int nb) {
    __shared__ int h[MAXB];
    for (int i = threadIdx.x; i < nb; i += blockDim.x) h[i] = 0;
    __syncthreads();
    int e0 = blockIdx.x * E_BLK;
    int e1 = min(e0 + E_BLK, n_edges);
    for (int e = e0 + threadIdx.x; e < e1; e += blockDim.x)
        atomicAdd(&h[row[e] >> 8], 1);
    __syncthreads();
    for (int i = threadIdx.x; i < nb; i += blockDim.x)
        hist_global[blockIdx.x * MAXB + i] = h[i];
}

// ---------------- K2: totals, exclusive scan, per-(block,bucket) bases -----
__global__ void scan_kernel(const int* __restrict__ hist_global,
                            int* __restrict__ bucket_off, int* __restrict__ base_global,
                            int nb, int nblk) {
    __shared__ int s[MAXB];
    int t = threadIdx.x;
    // per-bucket total
    int v = 0;
    if (t < nb) {
        for (int b = 0; b < nblk; ++b) v += hist_global[b * MAXB + t];
    }
    s[t] = v;
    __syncthreads();
    for (int o = 1; o < MAXB; o <<= 1) {
        int x = (t >= o) ? s[t - o] : 0;
        __syncthreads();
        s[t] += x;
        __syncthreads();
    }
    if (t < nb) {
        int running = s[t] - v;  // exclusive
        bucket_off[t] = running;
        for (int b = 0; b < nblk; ++b) {
            base_global[b * MAXB + t] = running;
            running += hist_global[b * MAXB + t];
        }
    }
    if (t == MAXB - 1) bucket_off[nb] = s[MAXB - 1];  // == n_edges
}

// ---------------- K3: partition into bucket regions (LDS cursors only) -----
__global__ void partition_kernel(const int* __restrict__ row, const int* __restrict__ col,
                                 const int* __restrict__ base_global,
                                 int2* __restrict__ binned, int n_edges, int nb) {
    __shared__ int cur[MAXB];
    for (int i = threadIdx.x; i < nb; i += blockDim.x)
        cur[i] = base_global[blockIdx.x * MAXB + i];
    __syncthreads();
    int e0 = blockIdx.x * E_BLK;
    int e1 = min(e0 + E_BLK, n_edges);
    for (int e = e0 + threadIdx.x; e < e1; e += blockDim.x) {
        int r = row[e];
        int pos = atomicAdd(&cur[r >> 8], 1);
        binned[pos] = make_int2(r, col[e]);
    }
}

// ---------------- K4: one block per bucket, LDS accumulate + epilogue ------
__global__ __launch_bounds__(256)
void aggregate_kernel(const float* __restrict__ feat,
                      const int* __restrict__ bucket_off,
                      const int2* __restrict__ binned,
                      float* __restrict__ out, int n_nodes) {
    __shared__ float acc[256 * D_FEAT];  // 64 KB: 256 rows x 64 dims
    __shared__ float degs[256];
    int b = blockIdx.x;
    int r0 = b << 8;
    int nrows = min(256, n_nodes - r0);

    // zero accumulators
    float4* a4 = reinterpret_cast<float4*>(acc);
    float4 z = make_float4(0.f, 0.f, 0.f, 0.f);
    for (int j = threadIdx.x; j < 256 * D_FEAT / 4; j += 256) a4[j] = z;
    degs[threadIdx.x] = 0.0f;
    __syncthreads();

    int start = bucket_off[b];
    int end = bucket_off[b + 1];
    int g = threadIdx.x >> 4;    // 16 groups of 16 threads, one edge each
    int sub = threadIdx.x & 15;  // which float4 of the 64-dim row
    #pragma unroll 2
    for (int i = start + g; i < end; i += 16) {
        int2 rc = binned[i];  // 16 lanes same addr -> broadcast
        const float4 v = *reinterpret_cast<const float4*>(
            feat + (size_t)rc.y * D_FEAT + sub * 4);
        int lr = (rc.x & 255) << 6;
        atomicAdd(&acc[lr + sub * 4 + 0], v.x);
        atomicAdd(&acc[lr + sub * 4 + 1], v.y);
        atomicAdd(&acc[lr + sub * 4 + 2], v.z);
        atomicAdd(&acc[lr + sub * 4 + 3], v.w);
        if (sub == 0) atomicAdd(&degs[rc.x & 255], 1.0f);
    }
    __syncthreads();

    // epilogue: out = feat + acc / max(deg,1), fully coalesced float4
    int total4 = nrows << 4;  // nrows * 64 / 4
    size_t base = (size_t)r0 * D_FEAT;
    for (int j = threadIdx.x; j < total4; j += 256) {
        int lrow = j >> 4;
        float inv = 1.0f / fmaxf(degs[lrow], 1.0f);
        float4 a = a4[j];
        const float4 f = *reinterpret_cast<const float4*>(feat + base + (size_t)j * 4);
        float4 o;
        o.x = f.x + a.x * inv;
        o.y = f.y + a.y * inv;
        o.z = f.z + a.z * inv;
        o.w = f.w + a.w * inv;
        *reinterpret_cast<float4*>(out + base + (size_t)j * 4) = o;
    }
}

extern "C" void kernel_launch(void* const* d_in, const int* in_sizes, int n_in,
                              void* d_out, int out_size, void* d_ws, size_t ws_size,
                              hipStream_t stream) {
    const float* feat = (const float*)d_in[0];
    const int* row = (const int*)d_in[1];
    const int* col = (const int*)d_in[2];
    float* out = (float*)d_out;

    const int n_nodes = in_sizes[0] / D_FEAT;
    const int n_edges = in_sizes[1];
    const int nb = (n_nodes + 255) >> 8;                 // 391
    const int nblk = (n_edges + E_BLK - 1) / E_BLK;      // 98

    // Workspace layout (no memsets needed — everything fully written):
    char* ws = (char*)d_ws;
    size_t p = 0;
    int* hist_global = (int*)(ws + p); p += (size_t)nblk * MAXB * 4;
    int* base_global = (int*)(ws + p); p += (size_t)nblk * MAXB * 4;
    int* bucket_off  = (int*)(ws + p); p += (size_t)(nb + 1) * 4;
    p = (p + 15) & ~(size_t)15;
    int2* binned     = (int2*)(ws + p); p += (size_t)n_edges * 8;

    hist_kernel<<<nblk, 256, 0, stream>>>(row, hist_global, n_edges, nb);
    scan_kernel<<<1, MAXB, 0, stream>>>(hist_global, bucket_off, base_global, nb, nblk);
    partition_kernel<<<nblk, 256, 0, stream>>>(row, col, base_global, binned, n_edges, nb);
    aggregate_kernel<<<nb, 256, 0, stream>>>(feat, bucket_off, binned, out, n_nodes);
}

// Round 5
// 233.910 us; speedup vs baseline: 3.6531x; 3.6531x over previous
//
#include <hip/hip_runtime.h>

// N=100000 nodes, E=1600000 edges, D=64.
#define D_FEAT 64
#define E_BLK 16384          // edges per hist/partition block
#define MAXB 512             // max buckets (nb = ceil(N/256) = 391)

// Edge packing: (local_row << 24) | col   (col < 2^24, local_row < 256)

// ---------------- K1: per-block bucket histogram (LDS only) ----------------
__global__ void hist_kernel(const int* __restrict__ row, int* __restrict__ hist_global,
                            int n_edges, int nb) {
    __shared__ int h[MAXB];
    for (int i = threadIdx.x; i < nb; i += blockDim.x) h[i] = 0;
    __syncthreads();
    int e0 = blockIdx.x * E_BLK;
    int e1 = min(e0 + E_BLK, n_edges);
    for (int e = e0 + threadIdx.x; e < e1; e += blockDim.x)
        atomicAdd(&h[row[e] >> 8], 1);
    __syncthreads();
    for (int i = threadIdx.x; i < nb; i += blockDim.x)
        hist_global[blockIdx.x * MAXB + i] = h[i];
}

// ---------------- K2: bucket totals, scan, per-(block,bucket) bases --------
__global__ void scan_kernel(const int* __restrict__ hist_global,
                            int* __restrict__ bucket_off, int* __restrict__ base_global,
                            int* __restrict__ offsets,
                            int nb, int nblk, int n_nodes, int n_edges) {
    __shared__ int s[MAXB];
    int t = threadIdx.x;
    int v = 0;
    if (t < nb)
        for (int b = 0; b < nblk; ++b) v += hist_global[b * MAXB + t];
    s[t] = v;
    __syncthreads();
    for (int o = 1; o < MAXB; o <<= 1) {
        int x = (t >= o) ? s[t - o] : 0;
        __syncthreads();
        s[t] += x;
        __syncthreads();
    }
    if (t < nb) {
        int running = s[t] - v;  // exclusive
        bucket_off[t] = running;
        for (int b = 0; b < nblk; ++b) {
            base_global[b * MAXB + t] = running;
            running += hist_global[b * MAXB + t];
        }
    }
    if (t == 0) {
        bucket_off[nb] = n_edges;
        offsets[n_nodes] = n_edges;
    }
}

// ---------------- K3: partition packed edges into bucket regions -----------
__global__ void partition_kernel(const int* __restrict__ row, const int* __restrict__ col,
                                 const int* __restrict__ base_global,
                                 int* __restrict__ binned, int n_edges, int nb) {
    __shared__ int cur[MAXB];
    for (int i = threadIdx.x; i < nb; i += blockDim.x)
        cur[i] = base_global[blockIdx.x * MAXB + i];
    __syncthreads();
    int e0 = blockIdx.x * E_BLK;
    int e1 = min(e0 + E_BLK, n_edges);
    for (int e = e0 + threadIdx.x; e < e1; e += blockDim.x) {
        int r = row[e];
        int pos = atomicAdd(&cur[r >> 8], 1);
        binned[pos] = ((r & 255) << 24) | col[e];
    }
}

// ---------------- K4: per-bucket exact CSR (one block per bucket) ----------
__global__ __launch_bounds__(256)
void csr_kernel(const int* __restrict__ binned, const int* __restrict__ bucket_off,
                int* __restrict__ offsets, int* __restrict__ sorted_col, int n_nodes) {
    __shared__ int cnt[256];
    __shared__ int sc[256];
    __shared__ int cur[256];
    int b = blockIdx.x;
    int r0 = b << 8;
    int t = threadIdx.x;
    int start = bucket_off[b];
    int end = bucket_off[b + 1];

    cnt[t] = 0;
    __syncthreads();
    for (int i = start + t; i < end; i += 256)
        atomicAdd(&cnt[((unsigned)binned[i]) >> 24], 1);
    __syncthreads();

    // exclusive scan of cnt
    int v = cnt[t];
    sc[t] = v;
    __syncthreads();
    for (int o = 1; o < 256; o <<= 1) {
        int x = (t >= o) ? sc[t - o] : 0;
        __syncthreads();
        sc[t] += x;
        __syncthreads();
    }
    int excl = sc[t] - v;
    cur[t] = excl;
    int r = r0 + t;
    if (r < n_nodes) offsets[r] = start + excl;
    __syncthreads();

    // scatter cols to exact CSR position (16KB dest window -> L2-local)
    for (int i = start + t; i < end; i += 256) {
        int p = binned[i];
        int lr = ((unsigned)p) >> 24;
        int pos = start + atomicAdd(&cur[lr], 1);
        sorted_col[pos] = p & 0xFFFFFF;
    }
}

// ---------------- K5: one wave per row; shfl-distributed col indices -------
__global__ __launch_bounds__(256)
void aggregate_kernel(const float* __restrict__ feat,
                      const int* __restrict__ offsets,
                      const int* __restrict__ sorted_col,
                      float* __restrict__ out, int n_nodes) {
    int wave = (blockIdx.x * blockDim.x + threadIdx.x) >> 6;
    int lane = threadIdx.x & 63;
    if (wave >= n_nodes) return;
    int start = offsets[wave];
    int end = offsets[wave + 1];
    int deg = end - start;
    int q = lane >> 4;     // 4 edge-groups
    int sub = lane & 15;   // float4 slot within the 64-dim row

    float4 acc0 = make_float4(0.f, 0.f, 0.f, 0.f);
    float4 acc1 = make_float4(0.f, 0.f, 0.f, 0.f);

    for (int base = 0; base < deg; base += 64) {
        int idx = base + lane;
        int colv = (idx < deg) ? sorted_col[start + idx] : 0;  // one coalesced load / 64 edges
        int m = min(64, deg - base);
        for (int i = 0; i < m; i += 8) {
            int j0 = i + q;
            int j1 = i + 4 + q;
            int c0 = __shfl(colv, j0, 64);
            int c1 = __shfl(colv, j1, 64);
            if (j0 < m) {
                const float4 v = *reinterpret_cast<const float4*>(
                    feat + (size_t)c0 * D_FEAT + sub * 4);
                acc0.x += v.x; acc0.y += v.y; acc0.z += v.z; acc0.w += v.w;
            }
            if (j1 < m) {
                const float4 v = *reinterpret_cast<const float4*>(
                    feat + (size_t)c1 * D_FEAT + sub * 4);
                acc1.x += v.x; acc1.y += v.y; acc1.z += v.z; acc1.w += v.w;
            }
        }
    }
    acc0.x += acc1.x; acc0.y += acc1.y; acc0.z += acc1.z; acc0.w += acc1.w;
    // fold the 4 edge-groups (lanes l, l^16, l^32 share `sub`)
    acc0.x += __shfl_xor(acc0.x, 16, 64);
    acc0.y += __shfl_xor(acc0.y, 16, 64);
    acc0.z += __shfl_xor(acc0.z, 16, 64);
    acc0.w += __shfl_xor(acc0.w, 16, 64);
    acc0.x += __shfl_xor(acc0.x, 32, 64);
    acc0.y += __shfl_xor(acc0.y, 32, 64);
    acc0.z += __shfl_xor(acc0.z, 32, 64);
    acc0.w += __shfl_xor(acc0.w, 32, 64);
    if (q == 0) {
        float inv = 1.0f / fmaxf((float)deg, 1.0f);
        size_t off = (size_t)wave * D_FEAT + sub * 4;
        const float4 f = *reinterpret_cast<const float4*>(feat + off);
        float4 o;
        o.x = f.x + acc0.x * inv;
        o.y = f.y + acc0.y * inv;
        o.z = f.z + acc0.z * inv;
        o.w = f.w + acc0.w * inv;
        *reinterpret_cast<float4*>(out + off) = o;
    }
}

extern "C" void kernel_launch(void* const* d_in, const int* in_sizes, int n_in,
                              void* d_out, int out_size, void* d_ws, size_t ws_size,
                              hipStream_t stream) {
    const float* feat = (const float*)d_in[0];
    const int* row = (const int*)d_in[1];
    const int* col = (const int*)d_in[2];
    float* out = (float*)d_out;

    const int n_nodes = in_sizes[0] / D_FEAT;
    const int n_edges = in_sizes[1];
    const int nb = (n_nodes + 255) >> 8;                 // 391
    const int nblk = (n_edges + E_BLK - 1) / E_BLK;      // 98

    // Workspace layout (everything fully written before read; no memsets):
    char* ws = (char*)d_ws;
    size_t p = 0;
    int* hist_global = (int*)(ws + p); p += (size_t)nblk * MAXB * 4;
    int* base_global = (int*)(ws + p); p += (size_t)nblk * MAXB * 4;
    int* bucket_off  = (int*)(ws + p); p += (size_t)(nb + 1) * 4;
    int* offsets     = (int*)(ws + p); p += (size_t)(n_nodes + 1) * 4;
    int* binned      = (int*)(ws + p); p += (size_t)n_edges * 4;
    int* sorted_col  = (int*)(ws + p); p += (size_t)n_edges * 4;

    hist_kernel<<<nblk, 256, 0, stream>>>(row, hist_global, n_edges, nb);
    scan_kernel<<<1, MAXB, 0, stream>>>(hist_global, bucket_off, base_global, offsets,
                                        nb, nblk, n_nodes, n_edges);
    partition_kernel<<<nblk, 256, 0, stream>>>(row, col, base_global, binned, n_edges, nb);
    csr_kernel<<<nb, 256, 0, stream>>>(binned, bucket_off, offsets, sorted_col, n_nodes);
    {
        long long total = (long long)n_nodes * 64;  // one wave per row
        int block = 256;
        int grid = (int)((total + block - 1) / block);
        aggregate_kernel<<<grid, block, 0, stream>>>(feat, offsets, sorted_col, out, n_nodes);
    }
}

// Round 6
// 230.143 us; speedup vs baseline: 3.7129x; 1.0164x over previous
//
#include <hip/hip_runtime.h>

// N=100000 nodes, E=1600000 edges, D=64.
#define D_FEAT 64
#define E_BLK 16384          // edges per hist/partition block
#define MAXB 512             // max buckets (nb = ceil(N/256) = 391)

// Edge packing: (local_row << 24) | col   (col < 2^24, local_row < 256)
// Histogram layout: hist_t[bucket * nblk + blk]  (transposed -> contiguous per bucket)

// ---------------- K1: per-block bucket histogram (LDS only) ----------------
__global__ void hist_kernel(const int* __restrict__ row, int* __restrict__ hist_t,
                            int n_edges, int nb, int nblk) {
    __shared__ int h[MAXB];
    for (int i = threadIdx.x; i < nb; i += blockDim.x) h[i] = 0;
    __syncthreads();
    int e0 = blockIdx.x * E_BLK;
    int e1 = min(e0 + E_BLK, n_edges);
    for (int e = e0 + threadIdx.x; e < e1; e += blockDim.x)
        atomicAdd(&h[row[e] >> 8], 1);
    __syncthreads();
    for (int i = threadIdx.x; i < nb; i += blockDim.x)
        hist_t[i * nblk + blockIdx.x] = h[i];
}

// ---------------- K2a: bucket totals + exclusive scan over buckets ---------
__global__ __launch_bounds__(MAXB)
void totals_scan_kernel(const int* __restrict__ hist_t, int* __restrict__ bucket_off,
                        int* __restrict__ offsets,
                        int nb, int nblk, int n_nodes, int n_edges) {
    __shared__ int s[MAXB];
    int t = threadIdx.x;
    int v = 0;
    if (t < nb) {
        const int* p = hist_t + (size_t)t * nblk;   // contiguous per thread
        for (int b = 0; b < nblk; ++b) v += p[b];
    }
    s[t] = v;
    __syncthreads();
    for (int o = 1; o < MAXB; o <<= 1) {
        int x = (t >= o) ? s[t - o] : 0;
        __syncthreads();
        s[t] += x;
        __syncthreads();
    }
    if (t < nb) bucket_off[t] = s[t] - v;  // exclusive
    if (t == 0) {
        bucket_off[nb] = n_edges;
        offsets[n_nodes] = n_edges;
    }
}

// ---------------- K2b: per-(bucket,block) bases (one block per bucket) -----
__global__ __launch_bounds__(128)
void bases_kernel(const int* __restrict__ hist_t, const int* __restrict__ bucket_off,
                  int* __restrict__ base_t, int nblk) {
    __shared__ int s[128];
    int b = blockIdx.x;          // bucket
    int j = threadIdx.x;         // partition-block index
    int v = (j < nblk) ? hist_t[(size_t)b * nblk + j] : 0;
    s[j] = v;
    __syncthreads();
    for (int o = 1; o < 128; o <<= 1) {
        int x = (j >= o) ? s[j - o] : 0;
        __syncthreads();
        s[j] += x;
        __syncthreads();
    }
    if (j < nblk)
        base_t[(size_t)b * nblk + j] = bucket_off[b] + s[j] - v;  // exclusive + bucket base
}

// ---------------- K3: partition packed edges into bucket regions -----------
__global__ void partition_kernel(const int* __restrict__ row, const int* __restrict__ col,
                                 const int* __restrict__ base_t,
                                 int* __restrict__ binned, int n_edges, int nb, int nblk) {
    __shared__ int cur[MAXB];
    for (int i = threadIdx.x; i < nb; i += blockDim.x)
        cur[i] = base_t[(size_t)i * nblk + blockIdx.x];
    __syncthreads();
    int e0 = blockIdx.x * E_BLK;
    int e1 = min(e0 + E_BLK, n_edges);
    for (int e = e0 + threadIdx.x; e < e1; e += blockDim.x) {
        int r = row[e];
        int pos = atomicAdd(&cur[r >> 8], 1);
        binned[pos] = ((r & 255) << 24) | col[e];
    }
}

// ---------------- K4: per-bucket exact CSR (one block per bucket) ----------
__global__ __launch_bounds__(256)
void csr_kernel(const int* __restrict__ binned, const int* __restrict__ bucket_off,
                int* __restrict__ offsets, int* __restrict__ sorted_col, int n_nodes) {
    __shared__ int cnt[256];
    __shared__ int sc[256];
    __shared__ int cur[256];
    int b = blockIdx.x;
    int r0 = b << 8;
    int t = threadIdx.x;
    int start = bucket_off[b];
    int end = bucket_off[b + 1];

    cnt[t] = 0;
    __syncthreads();
    for (int i = start + t; i < end; i += 256)
        atomicAdd(&cnt[((unsigned)binned[i]) >> 24], 1);
    __syncthreads();

    int v = cnt[t];
    sc[t] = v;
    __syncthreads();
    for (int o = 1; o < 256; o <<= 1) {
        int x = (t >= o) ? sc[t - o] : 0;
        __syncthreads();
        sc[t] += x;
        __syncthreads();
    }
    int excl = sc[t] - v;
    cur[t] = excl;
    int r = r0 + t;
    if (r < n_nodes) offsets[r] = start + excl;
    __syncthreads();

    for (int i = start + t; i < end; i += 256) {
        int p = binned[i];
        int lr = ((unsigned)p) >> 24;
        int pos = start + atomicAdd(&cur[lr], 1);
        sorted_col[pos] = p & 0xFFFFFF;
    }
}

// ---------------- K5: one wave per row; shfl-distributed col indices -------
__global__ __launch_bounds__(256)
void aggregate_kernel(const float* __restrict__ feat,
                      const int* __restrict__ offsets,
                      const int* __restrict__ sorted_col,
                      float* __restrict__ out, int n_nodes) {
    int wave = (blockIdx.x * blockDim.x + threadIdx.x) >> 6;
    int lane = threadIdx.x & 63;
    if (wave >= n_nodes) return;
    int start = offsets[wave];
    int end = offsets[wave + 1];
    int deg = end - start;
    int q = lane >> 4;     // 4 edge-groups
    int sub = lane & 15;   // float4 slot within the 64-dim row

    float4 acc0 = make_float4(0.f, 0.f, 0.f, 0.f);
    float4 acc1 = make_float4(0.f, 0.f, 0.f, 0.f);

    for (int base = 0; base < deg; base += 64) {
        int idx = base + lane;
        int colv = (idx < deg) ? sorted_col[start + idx] : 0;  // one coalesced load / 64 edges
        int m = min(64, deg - base);
        for (int i = 0; i < m; i += 8) {
            int j0 = i + q;
            int j1 = i + 4 + q;
            int c0 = __shfl(colv, j0, 64);
            int c1 = __shfl(colv, j1, 64);
            if (j0 < m) {
                const float4 v = *reinterpret_cast<const float4*>(
                    feat + (size_t)c0 * D_FEAT + sub * 4);
                acc0.x += v.x; acc0.y += v.y; acc0.z += v.z; acc0.w += v.w;
            }
            if (j1 < m) {
                const float4 v = *reinterpret_cast<const float4*>(
                    feat + (size_t)c1 * D_FEAT + sub * 4);
                acc1.x += v.x; acc1.y += v.y; acc1.z += v.z; acc1.w += v.w;
            }
        }
    }
    acc0.x += acc1.x; acc0.y += acc1.y; acc0.z += acc1.z; acc0.w += acc1.w;
    acc0.x += __shfl_xor(acc0.x, 16, 64);
    acc0.y += __shfl_xor(acc0.y, 16, 64);
    acc0.z += __shfl_xor(acc0.z, 16, 64);
    acc0.w += __shfl_xor(acc0.w, 16, 64);
    acc0.x += __shfl_xor(acc0.x, 32, 64);
    acc0.y += __shfl_xor(acc0.y, 32, 64);
    acc0.z += __shfl_xor(acc0.z, 32, 64);
    acc0.w += __shfl_xor(acc0.w, 32, 64);
    if (q == 0) {
        float inv = 1.0f / fmaxf((float)deg, 1.0f);
        size_t off = (size_t)wave * D_FEAT + sub * 4;
        const float4 f = *reinterpret_cast<const float4*>(feat + off);
        float4 o;
        o.x = f.x + acc0.x * inv;
        o.y = f.y + acc0.y * inv;
        o.z = f.z + acc0.z * inv;
        o.w = f.w + acc0.w * inv;
        *reinterpret_cast<float4*>(out + off) = o;
    }
}

extern "C" void kernel_launch(void* const* d_in, const int* in_sizes, int n_in,
                              void* d_out, int out_size, void* d_ws, size_t ws_size,
                              hipStream_t stream) {
    const float* feat = (const float*)d_in[0];
    const int* row = (const int*)d_in[1];
    const int* col = (const int*)d_in[2];
    float* out = (float*)d_out;

    const int n_nodes = in_sizes[0] / D_FEAT;
    const int n_edges = in_sizes[1];
    const int nb = (n_nodes + 255) >> 8;                 // 391
    const int nblk = (n_edges + E_BLK - 1) / E_BLK;      // 98

    // Workspace layout (everything fully written before read; no memsets):
    char* ws = (char*)d_ws;
    size_t p = 0;
    int* hist_t     = (int*)(ws + p); p += (size_t)nb * nblk * 4;
    int* base_t     = (int*)(ws + p); p += (size_t)nb * nblk * 4;
    int* bucket_off = (int*)(ws + p); p += (size_t)(nb + 1) * 4;
    int* offsets    = (int*)(ws + p); p += (size_t)(n_nodes + 1) * 4;
    int* binned     = (int*)(ws + p); p += (size_t)n_edges * 4;
    int* sorted_col = (int*)(ws + p); p += (size_t)n_edges * 4;

    hist_kernel<<<nblk, 256, 0, stream>>>(row, hist_t, n_edges, nb, nblk);
    totals_scan_kernel<<<1, MAXB, 0, stream>>>(hist_t, bucket_off, offsets,
                                               nb, nblk, n_nodes, n_edges);
    bases_kernel<<<nb, 128, 0, stream>>>(hist_t, bucket_off, base_t, nblk);
    partition_kernel<<<nblk, 256, 0, stream>>>(row, col, base_t, binned, n_edges, nb, nblk);
    csr_kernel<<<nb, 256, 0, stream>>>(binned, bucket_off, offsets, sorted_col, n_nodes);
    {
        long long total = (long long)n_nodes * 64;  // one wave per row
        int block = 256;
        int grid = (int)((total + block - 1) / block);
        aggregate_kernel<<<grid, block, 0, stream>>>(feat, offsets, sorted_col, out, n_nodes);
    }
}

// Round 7
// 179.722 us; speedup vs baseline: 4.7546x; 1.2805x over previous
//
#include <hip/hip_runtime.h>

// N=100000 nodes, E=1600000 edges, D=64.
#define D_FEAT 64
#define E_BLK 2048           // edges per hist/partition block -> 782 blocks (~3/CU)
#define MAXB 512             // max buckets (nb = ceil(N/256) = 391)

// Edge packing: (local_row << 24) | col   (col < 2^24, local_row < 256)
// hist_t layout:     [bucket * nblk + blk]   (contiguous per bucket, for bases)
// base_local layout: [blk * MAXB + bucket]   (contiguous per block, for partition)

__device__ inline unsigned short f2bf(float f) {
    unsigned u = __float_as_uint(f);
    u += 0x7FFFu + ((u >> 16) & 1u);   // RNE
    return (unsigned short)(u >> 16);
}
__device__ inline float bf2f(unsigned short u) {
    return __uint_as_float(((unsigned)u) << 16);
}

// ---------------- K1: per-block bucket histogram (LDS only) ----------------
__global__ __launch_bounds__(256)
void hist_kernel(const int* __restrict__ row, int* __restrict__ hist_t,
                 int n_edges, int nb, int nblk) {
    __shared__ int h[MAXB];
    for (int i = threadIdx.x; i < nb; i += 256) h[i] = 0;
    __syncthreads();
    int e0 = blockIdx.x * E_BLK;
    int e1 = min(e0 + E_BLK, n_edges);
    for (int e = e0 + threadIdx.x; e < e1; e += 256)
        atomicAdd(&h[row[e] >> 8], 1);
    __syncthreads();
    for (int i = threadIdx.x; i < nb; i += 256)
        hist_t[(size_t)i * nblk + blockIdx.x] = h[i];
}

// ---------------- K2: per-bucket scan over partition blocks ----------------
// One block per bucket: exclusive scan of hist_t[bucket][*] -> base_local,
// and the bucket total.
__global__ __launch_bounds__(256)
void bases_kernel(const int* __restrict__ hist_t, int* __restrict__ base_local,
                  int* __restrict__ bucket_total, int nblk) {
    __shared__ int s[256];
    int b = blockIdx.x;
    int t = threadIdx.x;
    const int* hp = hist_t + (size_t)b * nblk;
    int v[4];
    int sum = 0;
    #pragma unroll
    for (int k = 0; k < 4; ++k) {
        int j = t * 4 + k;
        v[k] = (j < nblk) ? hp[j] : 0;
        sum += v[k];
    }
    s[t] = sum;
    __syncthreads();
    for (int o = 1; o < 256; o <<= 1) {
        int x = (t >= o) ? s[t - o] : 0;
        __syncthreads();
        s[t] += x;
        __syncthreads();
    }
    int run = s[t] - sum;  // exclusive prefix of this thread's chunk
    if (t == 255) bucket_total[b] = s[255];
    #pragma unroll
    for (int k = 0; k < 4; ++k) {
        int j = t * 4 + k;
        if (j < nblk) base_local[(size_t)j * MAXB + b] = run;
        run += v[k];
    }
}

// ---------------- K3: exclusive scan of bucket totals ----------------------
__global__ __launch_bounds__(MAXB)
void scan_off_kernel(const int* __restrict__ bucket_total, int* __restrict__ bucket_off,
                     int* __restrict__ offsets, int nb, int n_nodes, int n_edges) {
    __shared__ int s[MAXB];
    int t = threadIdx.x;
    int v = (t < nb) ? bucket_total[t] : 0;
    s[t] = v;
    __syncthreads();
    for (int o = 1; o < MAXB; o <<= 1) {
        int x = (t >= o) ? s[t - o] : 0;
        __syncthreads();
        s[t] += x;
        __syncthreads();
    }
    if (t < nb) bucket_off[t] = s[t] - v;
    if (t == 0) {
        bucket_off[nb] = n_edges;
        offsets[n_nodes] = n_edges;
    }
}

// ---------------- K4: partition packed edges into bucket regions -----------
__global__ __launch_bounds__(256)
void partition_kernel(const int* __restrict__ row, const int* __restrict__ col,
                      const int* __restrict__ bucket_off, const int* __restrict__ base_local,
                      int* __restrict__ binned, int n_edges, int nb) {
    __shared__ int cur[MAXB];
    const int* bl = base_local + (size_t)blockIdx.x * MAXB;  // contiguous
    for (int i = threadIdx.x; i < nb; i += 256)
        cur[i] = bucket_off[i] + bl[i];
    __syncthreads();
    int e0 = blockIdx.x * E_BLK;
    int e1 = min(e0 + E_BLK, n_edges);
    for (int e = e0 + threadIdx.x; e < e1; e += 256) {
        int r = row[e];
        int pos = atomicAdd(&cur[r >> 8], 1);
        binned[pos] = ((r & 255) << 24) | col[e];
    }
}

// ---------------- K5: per-bucket exact CSR (one block per bucket) ----------
__global__ __launch_bounds__(256)
void csr_kernel(const int* __restrict__ binned, const int* __restrict__ bucket_off,
                int* __restrict__ offsets, int* __restrict__ sorted_col, int n_nodes) {
    __shared__ int cnt[256];
    __shared__ int sc[256];
    __shared__ int cur[256];
    int b = blockIdx.x;
    int r0 = b << 8;
    int t = threadIdx.x;
    int start = bucket_off[b];
    int end = bucket_off[b + 1];

    cnt[t] = 0;
    __syncthreads();
    for (int i = start + t; i < end; i += 256)
        atomicAdd(&cnt[((unsigned)binned[i]) >> 24], 1);
    __syncthreads();

    int v = cnt[t];
    sc[t] = v;
    __syncthreads();
    for (int o = 1; o < 256; o <<= 1) {
        int x = (t >= o) ? sc[t - o] : 0;
        __syncthreads();
        sc[t] += x;
        __syncthreads();
    }
    int excl = sc[t] - v;
    cur[t] = excl;
    int r = r0 + t;
    if (r < n_nodes) offsets[r] = start + excl;
    __syncthreads();

    for (int i = start + t; i < end; i += 256) {
        int p = binned[i];
        int lr = ((unsigned)p) >> 24;
        int pos = start + atomicAdd(&cur[lr], 1);
        sorted_col[pos] = p & 0xFFFFFF;
    }
}

// ---------------- K6: fp32 -> bf16 copy of the feature table ---------------
__global__ __launch_bounds__(256)
void tobf16_kernel(const float* __restrict__ feat, unsigned short* __restrict__ feat_bf,
                   int n_elem4) {
    int i = blockIdx.x * 256 + threadIdx.x;
    if (i >= n_elem4) return;
    float4 f = reinterpret_cast<const float4*>(feat)[i];
    ushort4 u;
    u.x = f2bf(f.x); u.y = f2bf(f.y); u.z = f2bf(f.z); u.w = f2bf(f.w);
    reinterpret_cast<ushort4*>(feat_bf)[i] = u;
}

// ---------------- K7: one wave per row; bf16 gather ------------------------
__global__ __launch_bounds__(256)
void aggregate_kernel(const float* __restrict__ feat,
                      const unsigned short* __restrict__ feat_bf,
                      const int* __restrict__ offsets,
                      const int* __restrict__ sorted_col,
                      float* __restrict__ out, int n_nodes) {
    int wave = (blockIdx.x * blockDim.x + threadIdx.x) >> 6;
    int lane = threadIdx.x & 63;
    if (wave >= n_nodes) return;
    int start = offsets[wave];
    int end = offsets[wave + 1];
    int deg = end - start;
    int q = lane >> 4;     // 4 edge-groups
    int sub = lane & 15;   // ushort4 slot within the 64-dim row

    float4 acc0 = make_float4(0.f, 0.f, 0.f, 0.f);
    float4 acc1 = make_float4(0.f, 0.f, 0.f, 0.f);

    for (int base = 0; base < deg; base += 64) {
        int idx = base + lane;
        int colv = (idx < deg) ? sorted_col[start + idx] : 0;  // one coalesced load / 64 edges
        int m = min(64, deg - base);
        for (int i = 0; i < m; i += 8) {
            int j0 = i + q;
            int j1 = i + 4 + q;
            int c0 = __shfl(colv, j0, 64);
            int c1 = __shfl(colv, j1, 64);
            if (j0 < m) {
                ushort4 v = *reinterpret_cast<const ushort4*>(
                    feat_bf + (size_t)c0 * D_FEAT + sub * 4);
                acc0.x += bf2f(v.x); acc0.y += bf2f(v.y);
                acc0.z += bf2f(v.z); acc0.w += bf2f(v.w);
            }
            if (j1 < m) {
                ushort4 v = *reinterpret_cast<const ushort4*>(
                    feat_bf + (size_t)c1 * D_FEAT + sub * 4);
                acc1.x += bf2f(v.x); acc1.y += bf2f(v.y);
                acc1.z += bf2f(v.z); acc1.w += bf2f(v.w);
            }
        }
    }
    acc0.x += acc1.x; acc0.y += acc1.y; acc0.z += acc1.z; acc0.w += acc1.w;
    acc0.x += __shfl_xor(acc0.x, 16, 64);
    acc0.y += __shfl_xor(acc0.y, 16, 64);
    acc0.z += __shfl_xor(acc0.z, 16, 64);
    acc0.w += __shfl_xor(acc0.w, 16, 64);
    acc0.x += __shfl_xor(acc0.x, 32, 64);
    acc0.y += __shfl_xor(acc0.y, 32, 64);
    acc0.z += __shfl_xor(acc0.z, 32, 64);
    acc0.w += __shfl_xor(acc0.w, 32, 64);
    if (q == 0) {
        float inv = 1.0f / fmaxf((float)deg, 1.0f);
        size_t off = (size_t)wave * D_FEAT + sub * 4;
        const float4 f = *reinterpret_cast<const float4*>(feat + off);
        float4 o;
        o.x = f.x + acc0.x * inv;
        o.y = f.y + acc0.y * inv;
        o.z = f.z + acc0.z * inv;
        o.w = f.w + acc0.w * inv;
        *reinterpret_cast<float4*>(out + off) = o;
    }
}

extern "C" void kernel_launch(void* const* d_in, const int* in_sizes, int n_in,
                              void* d_out, int out_size, void* d_ws, size_t ws_size,
                              hipStream_t stream) {
    const float* feat = (const float*)d_in[0];
    const int* row = (const int*)d_in[1];
    const int* col = (const int*)d_in[2];
    float* out = (float*)d_out;

    const int n_nodes = in_sizes[0] / D_FEAT;
    const int n_edges = in_sizes[1];
    const int nb = (n_nodes + 255) >> 8;                  // 391
    const int nblk = (n_edges + E_BLK - 1) / E_BLK;       // 782

    // Workspace layout. Overlay: feat_bf (written AFTER csr consumes binned)
    // shares space with {binned, hist_t, base_local}, whose lifetime ends at csr.
    char* ws = (char*)d_ws;
    size_t sort_bytes = (size_t)n_edges * 4                 // binned
                      + (size_t)nb * nblk * 4               // hist_t
                      + (size_t)nblk * MAXB * 4;            // base_local
    size_t bf_bytes = (size_t)n_nodes * D_FEAT * 2;         // 12.8 MB
    size_t OV = (sort_bytes > bf_bytes ? sort_bytes : bf_bytes);
    OV = (OV + 15) & ~(size_t)15;

    unsigned short* feat_bf = (unsigned short*)ws;
    int* binned     = (int*)ws;
    int* hist_t     = (int*)(ws + (size_t)n_edges * 4);
    int* base_local = hist_t + (size_t)nb * nblk;

    size_t p = OV;
    int* sorted_col   = (int*)(ws + p); p += (size_t)n_edges * 4;
    int* offsets      = (int*)(ws + p); p += (size_t)(n_nodes + 1) * 4;
    int* bucket_off   = (int*)(ws + p); p += (size_t)(nb + 1) * 4;
    int* bucket_total = (int*)(ws + p); p += (size_t)nb * 4;

    hist_kernel<<<nblk, 256, 0, stream>>>(row, hist_t, n_edges, nb, nblk);
    bases_kernel<<<nb, 256, 0, stream>>>(hist_t, base_local, bucket_total, nblk);
    scan_off_kernel<<<1, MAXB, 0, stream>>>(bucket_total, bucket_off, offsets,
                                            nb, n_nodes, n_edges);
    partition_kernel<<<nblk, 256, 0, stream>>>(row, col, bucket_off, base_local,
                                               binned, n_edges, nb);
    csr_kernel<<<nb, 256, 0, stream>>>(binned, bucket_off, offsets, sorted_col, n_nodes);
    {
        int n_elem4 = n_nodes * D_FEAT / 4;  // 1.6M
        tobf16_kernel<<<(n_elem4 + 255) / 256, 256, 0, stream>>>(feat, feat_bf, n_elem4);
    }
    {
        long long total = (long long)n_nodes * 64;  // one wave per row
        int block = 256;
        int grid = (int)((total + block - 1) / block);
        aggregate_kernel<<<grid, block, 0, stream>>>(feat, feat_bf, offsets, sorted_col,
                                                     out, n_nodes);
    }
}